// Round 3
// baseline (1374.289 us; speedup 1.0000x reference)
//
#include <hip/hip_runtime.h>
#include <hip/hip_bf16.h>
#include <math.h>

#define NPTS 4096
#define CIN 64
#define COUT 64
#define BATCH 8
#define KNN 20
#define NCHUNK 4
#define CHUNK (NPTS / NCHUNK)

// ---------------------------------------------------------------------------
// K0: transpose x -> xT[b][n][c], xx[b][n] = sum_c x^2, and the two small
// GEMMs u[b][n][o] = sum_c (W[o,c]-W[o,64+c])*x[b,c,n],
//       v[b][n][o] = sum_c  W[o,64+c]      *x[b,c,n]
// (h[b,o,n,k] = u[b,n,o] + v[b,idx[b,n,k],o] by linearity of the edge-conv.)
// ---------------------------------------------------------------------------
__global__ __launch_bounds__(256) void k_prep(const float* __restrict__ x,
                                              const float* __restrict__ W,
                                              float* __restrict__ xT,
                                              float* __restrict__ xx,
                                              float* __restrict__ u,
                                              float* __restrict__ v) {
    __shared__ float xs[64][65];   // [c][j], padded: transpose read is conflict-free
    __shared__ float wd[64][64];   // [c][o] = W1 - W2
    __shared__ float wv[64][64];   // [c][o] = W2
    const int t = threadIdx.x;
    const int b = blockIdx.y;
    const int n0 = blockIdx.x * 64;

    const float* xb = x + (size_t)b * CIN * NPTS;
#pragma unroll
    for (int i = 0; i < 16; ++i) {          // load x tile, coalesced per c-row
        int flat = t + 256 * i;             // 4096 elements
        int c = flat >> 6, j = flat & 63;
        xs[c][j] = xb[(size_t)c * NPTS + n0 + j];
    }
#pragma unroll
    for (int i = 0; i < 16; ++i) {          // load/transform W (32 KB, L2-cached)
        int flat = t + 256 * i;
        int o = flat & 63, c = flat >> 6;
        float w1 = W[o * 128 + c];
        float w2 = W[o * 128 + 64 + c];
        wd[c][o] = w1 - w2;
        wv[c][o] = w2;
    }
    __syncthreads();

#pragma unroll
    for (int i = 0; i < 16; ++i) {          // write xT, coalesced over c
        int flat = t + 256 * i;
        int j = flat >> 6, c = flat & 63;
        xT[((size_t)b * NPTS + n0 + j) * 64 + c] = xs[c][j];
    }
    if (t < 64) {                           // xx: sequential over c
        float s = 0.f;
#pragma unroll
        for (int c = 0; c < 64; ++c) { float a = xs[c][t]; s += a * a; }
        xx[b * NPTS + n0 + t] = s;
    }

    // u, v: each thread owns channel o = t&63 for 16 point-columns j = (t>>6)+4i
    const int o = t & 63, jb = t >> 6;
    float au[16], av[16];
#pragma unroll
    for (int i = 0; i < 16; ++i) { au[i] = 0.f; av[i] = 0.f; }
    for (int c = 0; c < 64; ++c) {
        float a = wd[c][o];                 // consecutive o -> conflict-free (2-way, free)
        float p = wv[c][o];
#pragma unroll
        for (int i = 0; i < 16; ++i) {
            float xc = xs[c][jb + 4 * i];   // wave-uniform -> LDS broadcast
            au[i] += a * xc;
            av[i] += p * xc;
        }
    }
#pragma unroll
    for (int i = 0; i < 16; ++i) {
        int j = jb + 4 * i;
        size_t base = ((size_t)b * NPTS + n0 + j) * 64 + o;
        u[base] = au[i];                    // coalesced over o
        v[base] = av[i];
    }
}

// ---------------------------------------------------------------------------
// K1: fused distance + top-20 per row over one candidate chunk.
// Thread-per-row; candidate column xT[b][m][:] is wave-uniform (one L1 line
// broadcast per load). Row tile lives in float4 row4[16] registers —
// __launch_bounds__(256,3) caps VGPR at ~170 so the compiler does NOT
// rematerialize the row loads inside the loop (round-2 failure: VGPR=60,
// row re-loaded from L1/L2 every candidate, 10x over VALU floor).
// Distance arithmetic is bit-identical to the round-2 passing version.
// ---------------------------------------------------------------------------
__global__ __launch_bounds__(256, 3) void k_knn(const float* __restrict__ xT,
                                                const float* __restrict__ xx,
                                                float* __restrict__ cval,
                                                int* __restrict__ cidx) {
    const int t = threadIdx.x;
    const int b = blockIdx.z;
    const int n = blockIdx.x * 256 + t;
    const int m0 = blockIdx.y * CHUNK;

    float4 row4[16];                        // 64 VGPRs, resident for the whole loop
    const float4* rp = (const float4*)(xT + ((size_t)b * NPTS + n) * 64);
#pragma unroll
    for (int q = 0; q < 16; ++q) row4[q] = rp[q];
    const float xxn = xx[b * NPTS + n];

    float vals[KNN];
    int   idxs[KNN];
#pragma unroll
    for (int k = 0; k < KNN; ++k) { vals[k] = -INFINITY; idxs[k] = -1; }

    const float4* colp = (const float4*)(xT + ((size_t)b * NPTS + m0) * 64);
    const float*  xxp  = xx + b * NPTS + m0;

#pragma unroll 2
    for (int mm = 0; mm < CHUNK; ++mm) {
        float4 acc = make_float4(0.f, 0.f, 0.f, 0.f);   // 4 partial sums
#pragma unroll
        for (int q = 0; q < 16; ++q) {
            float4 c4 = colp[mm * 16 + q];              // uniform address -> L1 broadcast
            acc.x += row4[q].x * c4.x;
            acc.y += row4[q].y * c4.y;
            acc.z += row4[q].z * c4.z;
            acc.w += row4[q].w * c4.w;
        }
        float inner = (acc.x + acc.y) + (acc.z + acc.w);
        float d = 2.f * inner - xxn - xxp[mm];
        if (d > vals[KNN - 1]) {            // divergent, but body is branchless
#pragma unroll
            for (int j = KNN - 1; j >= 0; --j) {
                float vj = vals[j];
                bool keep = (vj >= d);       // ties keep earlier (lower m) first
                float vprev = (j == 0) ? INFINITY : vals[j - 1];
                int   iprev = (j == 0) ? 0 : idxs[j - 1];
                bool prevge = (vprev >= d);
                vals[j] = keep ? vj : (prevge ? d : vprev);
                idxs[j] = keep ? idxs[j] : (prevge ? (m0 + mm) : iprev);
            }
        }
    }

    size_t rbase = ((size_t)(b * NPTS + n) * NCHUNK + blockIdx.y) * KNN;
#pragma unroll
    for (int k = 0; k < KNN; ++k) { cval[rbase + k] = vals[k]; cidx[rbase + k] = idxs[k]; }
}

// ---------------------------------------------------------------------------
// K2: K-way merge of the per-chunk sorted top-20 lists -> final top-20 index
// set. Strict '>' keeps the lowest chunk on ties (chunk c covers ascending m
// ranges -> lowest-index-first, matching lax.top_k). Tiny kernel.
// ---------------------------------------------------------------------------
__global__ __launch_bounds__(256) void k_merge(const float* __restrict__ cval,
                                               const int* __restrict__ cidx,
                                               int* __restrict__ idxf) {
    const int r = blockIdx.x * 256 + threadIdx.x;   // 0..B*N-1
    const float* v0 = cval + (size_t)r * (NCHUNK * KNN);
    const int*   i0 = cidx + (size_t)r * (NCHUNK * KNN);
    int p[NCHUNK];
#pragma unroll
    for (int c = 0; c < NCHUNK; ++c) p[c] = 0;
    int* op = idxf + (size_t)r * KNN;
    for (int k = 0; k < KNN; ++k) {
        float best = -INFINITY; int bc = 0;
#pragma unroll
        for (int c = 0; c < NCHUNK; ++c) {
            float hv = v0[c * KNN + p[c]];          // L1-cached re-reads
            if (hv > best) { best = hv; bc = c; }
        }
        op[k] = i0[bc * KNN + p[bc]];
        p[bc]++;
    }
}

// ---------------------------------------------------------------------------
// K4: single gather pass: h = u[n][o] + v[m][o]; accumulate sum/sumsq per
// channel (block partials, no atomics -> deterministic) and per-(n,o) max/min.
// Wave = 64 lanes = 64 channels; v rows are 256 B coalesced L2-resident reads.
// ---------------------------------------------------------------------------
__global__ __launch_bounds__(256) void k_gather(const float* __restrict__ u,
                                                const float* __restrict__ v,
                                                const int* __restrict__ idxf,
                                                float* __restrict__ hmax,
                                                float* __restrict__ hmin,
                                                float* __restrict__ part) {
    const int t = threadIdx.x;
    const int o = t & 63, w = t >> 6;
    const int b = blockIdx.y;
    const int n0 = blockIdx.x * 64;
    const float* vb = v + (size_t)b * NPTS * 64;
    float su = 0.f, sq = 0.f;
    for (int r = 0; r < 16; ++r) {
        int n = n0 + w + 4 * r;
        size_t nb = (size_t)b * NPTS + n;
        float hu = u[nb * 64 + o];
        const int* ip = idxf + nb * KNN;    // wave-uniform reads
        float mx = -INFINITY, mn = INFINITY;
#pragma unroll 4
        for (int k = 0; k < KNN; ++k) {
            int m = ip[k];
            float h = hu + vb[(size_t)m * 64 + o];
            mx = fmaxf(mx, h);
            mn = fminf(mn, h);
            su += h;
            sq += h * h;
        }
        hmax[nb * 64 + o] = mx;
        hmin[nb * 64 + o] = mn;
    }
    __shared__ float red[4][128];
    red[w][o] = su;
    red[w][64 + o] = sq;
    __syncthreads();
    if (t < 128) {
        float s = red[0][t] + red[1][t] + red[2][t] + red[3][t];
        part[(size_t)(blockIdx.y * 64 + blockIdx.x) * 128 + t] = s;
    }
}

// ---------------------------------------------------------------------------
// K5: reduce 512 block partials -> mean/var -> fused scale/shift.
// Round-2 version was 64 threads x 512 serial latency-bound iterations;
// now 256 threads (4 row-slices) + LDS reduce.
// ---------------------------------------------------------------------------
__global__ __launch_bounds__(256) void k_stats(const float* __restrict__ part,
                                               const float* __restrict__ gamma,
                                               const float* __restrict__ beta,
                                               float* __restrict__ ab) {
    __shared__ float rs[4][64], rq[4][64];
    const int t = threadIdx.x;
    const int o = t & 63, sl = t >> 6;      // 4 slices of 128 rows
    float s = 0.f, q = 0.f;
    for (int r = sl; r < 512; r += 4) {
        s += part[r * 128 + o];
        q += part[r * 128 + 64 + o];
    }
    rs[sl][o] = s; rq[sl][o] = q;
    __syncthreads();
    if (t < 64) {
        float ss = rs[0][t] + rs[1][t] + rs[2][t] + rs[3][t];
        float qq = rq[0][t] + rq[1][t] + rq[2][t] + rq[3][t];
        const float cnt = (float)BATCH * NPTS * KNN;
        float mean = ss / cnt;
        float var = qq / cnt - mean * mean;
        float rstd = rsqrtf(var + 1e-5f);
        float a = gamma[t] * rstd;
        ab[t] = a;
        ab[64 + t] = beta[t] - mean * a;
    }
}

// ---------------------------------------------------------------------------
// K6: epilogue. Monotone affine+LeakyReLU => max over k is at hmax (scale>=0)
// or hmin (scale<0). LDS transpose for coalesced out[b][o][n] writes.
// ---------------------------------------------------------------------------
__global__ __launch_bounds__(256) void k_out(const float* __restrict__ hmax,
                                             const float* __restrict__ hmin,
                                             const float* __restrict__ ab,
                                             float* __restrict__ out) {
    __shared__ float ts[64][65];
    const int t = threadIdx.x;
    const int b = blockIdx.y;
    const int n0 = blockIdx.x * 64;
#pragma unroll
    for (int i = 0; i < 16; ++i) {
        int flat = t + 256 * i;
        int j = flat >> 6, o = flat & 63;
        size_t nb = ((size_t)b * NPTS + n0 + j) * 64 + o;
        float a = ab[o], sh = ab[64 + o];
        float hval = (a >= 0.f) ? hmax[nb] : hmin[nb];
        float val = a * hval + sh;
        val = (val >= 0.f) ? val : 0.2f * val;
        ts[o][j] = val;
    }
    __syncthreads();
#pragma unroll
    for (int i = 0; i < 16; ++i) {
        int flat = t + 256 * i;
        int o = flat >> 6, j = flat & 63;
        out[((size_t)b * 64 + o) * NPTS + n0 + j] = ts[o][j];
    }
}

// ---------------------------------------------------------------------------
extern "C" void kernel_launch(void* const* d_in, const int* in_sizes, int n_in,
                              void* d_out, int out_size, void* d_ws, size_t ws_size,
                              hipStream_t stream) {
    const float* x     = (const float*)d_in[0];   // (8, 64, 4096)
    const float* W     = (const float*)d_in[1];   // (64, 128)
    const float* gamma = (const float*)d_in[2];   // (64,)
    const float* beta  = (const float*)d_in[3];   // (64,)
    float* out = (float*)d_out;                   // (8, 64, 4096)

    float* ws = (float*)d_ws;
    const size_t BN = (size_t)BATCH * NPTS;       // 32768
    size_t off = 0;
    float* xT   = ws + off; off += BN * 64;
    float* xx   = ws + off; off += BN;
    float* u    = ws + off; off += BN * 64;
    float* v    = ws + off; off += BN * 64;
    float* cval = ws + off; off += BN * NCHUNK * KNN;
    int*   cidx = (int*)(ws + off); off += BN * NCHUNK * KNN;
    int*   idxf = (int*)(ws + off); off += BN * KNN;
    float* hmx  = ws + off; off += BN * 64;
    float* hmn  = ws + off; off += BN * 64;
    float* part = ws + off; off += 512 * 128;
    float* ab   = ws + off; off += 128;
    // total ~16.5M floats (~66 MB), same footprint as the passing round-2 run.

    k_prep  <<<dim3(64, BATCH), 256, 0, stream>>>(x, W, xT, xx, u, v);
    k_knn   <<<dim3(16, NCHUNK, BATCH), 256, 0, stream>>>(xT, xx, cval, cidx);
    k_merge <<<dim3((int)(BN / 256)), 256, 0, stream>>>(cval, cidx, idxf);
    k_gather<<<dim3(64, BATCH), 256, 0, stream>>>(u, v, idxf, hmx, hmn, part);
    k_stats <<<1, 256, 0, stream>>>(part, gamma, beta, ab);
    k_out   <<<dim3(64, BATCH), 256, 0, stream>>>(hmx, hmn, ab, out);
}

// Round 4
// 1176.841 us; speedup vs baseline: 1.1678x; 1.1678x over previous
//
#include <hip/hip_runtime.h>
#include <hip/hip_bf16.h>
#include <math.h>

#define NPTS 4096
#define CIN 64
#define COUT 64
#define BATCH 8
#define KNN 20
#define NCHUNK 4
#define CHUNK (NPTS / NCHUNK)

// ---------------------------------------------------------------------------
// K0: transpose x -> xT[b][n][c], xx[b][n] = sum_c x^2, and the two small
// GEMMs u[b][n][o] = sum_c (W[o,c]-W[o,64+c])*x[b,c,n],
//       v[b][n][o] = sum_c  W[o,64+c]      *x[b,c,n]
// (h[b,o,n,k] = u[b,n,o] + v[b,idx[b,n,k],o] by linearity of the edge-conv.)
// ---------------------------------------------------------------------------
__global__ __launch_bounds__(256) void k_prep(const float* __restrict__ x,
                                              const float* __restrict__ W,
                                              float* __restrict__ xT,
                                              float* __restrict__ xx,
                                              float* __restrict__ u,
                                              float* __restrict__ v) {
    __shared__ float xs[64][65];   // [c][j], padded: transpose read is conflict-free
    __shared__ float wd[64][64];   // [c][o] = W1 - W2
    __shared__ float wv[64][64];   // [c][o] = W2
    const int t = threadIdx.x;
    const int b = blockIdx.y;
    const int n0 = blockIdx.x * 64;

    const float* xb = x + (size_t)b * CIN * NPTS;
#pragma unroll
    for (int i = 0; i < 16; ++i) {          // load x tile, coalesced per c-row
        int flat = t + 256 * i;             // 4096 elements
        int c = flat >> 6, j = flat & 63;
        xs[c][j] = xb[(size_t)c * NPTS + n0 + j];
    }
#pragma unroll
    for (int i = 0; i < 16; ++i) {          // load/transform W (32 KB, L2-cached)
        int flat = t + 256 * i;
        int o = flat & 63, c = flat >> 6;
        float w1 = W[o * 128 + c];
        float w2 = W[o * 128 + 64 + c];
        wd[c][o] = w1 - w2;
        wv[c][o] = w2;
    }
    __syncthreads();

#pragma unroll
    for (int i = 0; i < 16; ++i) {          // write xT, coalesced over c
        int flat = t + 256 * i;
        int j = flat >> 6, c = flat & 63;
        xT[((size_t)b * NPTS + n0 + j) * 64 + c] = xs[c][j];
    }
    if (t < 64) {                           // xx: sequential over c
        float s = 0.f;
#pragma unroll
        for (int c = 0; c < 64; ++c) { float a = xs[c][t]; s += a * a; }
        xx[b * NPTS + n0 + t] = s;
    }

    // u, v: each thread owns channel o = t&63 for 16 point-columns j = (t>>6)+4i
    const int o = t & 63, jb = t >> 6;
    float au[16], av[16];
#pragma unroll
    for (int i = 0; i < 16; ++i) { au[i] = 0.f; av[i] = 0.f; }
    for (int c = 0; c < 64; ++c) {
        float a = wd[c][o];                 // consecutive o -> conflict-free (2-way, free)
        float p = wv[c][o];
#pragma unroll
        for (int i = 0; i < 16; ++i) {
            float xc = xs[c][jb + 4 * i];   // wave-uniform -> LDS broadcast
            au[i] += a * xc;
            av[i] += p * xc;
        }
    }
#pragma unroll
    for (int i = 0; i < 16; ++i) {
        int j = jb + 4 * i;
        size_t base = ((size_t)b * NPTS + n0 + j) * 64 + o;
        u[base] = au[i];                    // coalesced over o
        v[base] = av[i];
    }
}

// ---------------------------------------------------------------------------
// K1: fused distance + top-20 per row over one candidate chunk.
// Thread-per-row. Three fixes vs R3 (same arithmetic, bit-exact selection):
//  (a) row4[] pinned in VGPRs via empty asm -- compiler was rematerializing
//      the 16 per-lane row loads EVERY candidate (1 KB/wave-load x16/iter
//      saturated the L1 pipe -> 52% VALUBusy stall).
//  (b) insert chain via v_med3_f32: vals[j]=med3(d,vals[j-1],vals[j]) walking
//      j downward == old shift-insert exactly (incl. tie order), 4 inst/step.
//  (c) batch-per-XCD block swizzle: hw round-robin (xcd=bid%8) -> b=bid&7
//      puts ONE batch's 1MB xT per 4MB L2 instead of all 8 MB on each.
// ---------------------------------------------------------------------------
__global__ __launch_bounds__(256, 2) void k_knn(const float* __restrict__ xT,
                                                const float* __restrict__ xx,
                                                float* __restrict__ cval,
                                                int* __restrict__ cidx) {
    const int t = threadIdx.x;
    const int bid = blockIdx.x + 16 * (blockIdx.y + NCHUNK * blockIdx.z);
    const int b = bid & 7;                  // XCD id under hw round-robin
    const int slot = bid >> 3;              // 0..63
    const int chunk = slot & (NCHUNK - 1);  // 0..3
    const int rowgrp = slot >> 2;           // 0..15
    const int n = rowgrp * 256 + t;
    const int m0 = chunk * CHUNK;

    float4 row4[16];                        // 64 VGPRs, pinned below
    const float4* rp = (const float4*)(xT + ((size_t)b * NPTS + n) * 64);
#pragma unroll
    for (int q = 0; q < 16; ++q) row4[q] = rp[q];
#pragma unroll
    for (int q = 0; q < 16; ++q) {          // opaque redefinition: no remat
        asm volatile("" : "+v"(row4[q].x), "+v"(row4[q].y),
                          "+v"(row4[q].z), "+v"(row4[q].w));
    }
    const float xxn = xx[b * NPTS + n];

    float vals[KNN];
    int   idxs[KNN];
#pragma unroll
    for (int k = 0; k < KNN; ++k) { vals[k] = -INFINITY; idxs[k] = -1; }

    const float4* colp = (const float4*)(xT + ((size_t)b * NPTS + m0) * 64);
    const float*  xxp  = xx + b * NPTS + m0;

#pragma unroll 2
    for (int mm = 0; mm < CHUNK; ++mm) {
        float4 acc = make_float4(0.f, 0.f, 0.f, 0.f);   // 4 partial sums
#pragma unroll
        for (int q = 0; q < 16; ++q) {
            float4 c4 = colp[mm * 16 + q];              // wave-uniform -> 1 line
            acc.x += row4[q].x * c4.x;
            acc.y += row4[q].y * c4.y;
            acc.z += row4[q].z * c4.z;
            acc.w += row4[q].w * c4.w;
        }
        float inner = (acc.x + acc.y) + (acc.z + acc.w);
        float d = 2.f * inner - xxn - xxp[mm];
        if (d > vals[KNN - 1]) {            // chain: descending j, old values
            const int midx = m0 + mm;
#pragma unroll
            for (int j = KNN - 1; j >= 1; --j) {
                bool kprev = (vals[j - 1] >= d);        // old vals[j-1]
                bool kj    = (vals[j] >= d);            // old vals[j]
                vals[j] = __builtin_amdgcn_fmed3f(d, vals[j - 1], vals[j]);
                idxs[j] = kj ? idxs[j] : (kprev ? midx : idxs[j - 1]);
            }
            bool k0 = (vals[0] >= d);
            vals[0] = fmaxf(vals[0], d);
            idxs[0] = k0 ? idxs[0] : midx;
        }
    }

    size_t rbase = ((size_t)(b * NPTS + n) * NCHUNK + chunk) * KNN;
#pragma unroll
    for (int k = 0; k < KNN; ++k) { cval[rbase + k] = vals[k]; cidx[rbase + k] = idxs[k]; }
}

// ---------------------------------------------------------------------------
// K2: K-way merge of the per-chunk sorted top-20 lists. All array indexing is
// compile-time (p[c], c unrolled) -> registers, no scratch. Strict '>' keeps
// the lowest chunk on ties (chunks cover ascending m) = lowest-index-first.
// ---------------------------------------------------------------------------
__global__ __launch_bounds__(256) void k_merge(const float* __restrict__ cval,
                                               const int* __restrict__ cidx,
                                               int* __restrict__ idxf) {
    const int r = blockIdx.x * 256 + threadIdx.x;   // 0..B*N-1
    const float* v0 = cval + (size_t)r * (NCHUNK * KNN);
    const int*   i0 = cidx + (size_t)r * (NCHUNK * KNN);
    int p[NCHUNK];
#pragma unroll
    for (int c = 0; c < NCHUNK; ++c) p[c] = 0;
    int* op = idxf + (size_t)r * KNN;
    for (int k = 0; k < KNN; ++k) {
        float best = -INFINITY; int besti = 0, bc = 0;
#pragma unroll
        for (int c = 0; c < NCHUNK; ++c) {
            float hv = v0[c * KNN + p[c]];          // L1-cached re-reads
            int   hi = i0[c * KNN + p[c]];
            bool g = hv > best;
            best = g ? hv : best;
            besti = g ? hi : besti;
            bc = g ? c : bc;
        }
        op[k] = besti;
#pragma unroll
        for (int c = 0; c < NCHUNK; ++c) p[c] += (bc == c);
    }
}

// ---------------------------------------------------------------------------
// K4: single gather pass: h = u[n][o] + v[m][o]; accumulate sum/sumsq per
// channel (block partials, no atomics -> deterministic) and per-(n,o) max/min.
// Wave = 64 lanes = 64 channels; v rows are 256 B coalesced L2-resident reads.
// ---------------------------------------------------------------------------
__global__ __launch_bounds__(256) void k_gather(const float* __restrict__ u,
                                                const float* __restrict__ v,
                                                const int* __restrict__ idxf,
                                                float* __restrict__ hmax,
                                                float* __restrict__ hmin,
                                                float* __restrict__ part) {
    const int t = threadIdx.x;
    const int o = t & 63, w = t >> 6;
    const int b = blockIdx.y;
    const int n0 = blockIdx.x * 64;
    const float* vb = v + (size_t)b * NPTS * 64;
    float su = 0.f, sq = 0.f;
    for (int r = 0; r < 16; ++r) {
        int n = n0 + w + 4 * r;
        size_t nb = (size_t)b * NPTS + n;
        float hu = u[nb * 64 + o];
        const int* ip = idxf + nb * KNN;    // wave-uniform reads
        float mx = -INFINITY, mn = INFINITY;
#pragma unroll 4
        for (int k = 0; k < KNN; ++k) {
            int m = ip[k];
            float h = hu + vb[(size_t)m * 64 + o];
            mx = fmaxf(mx, h);
            mn = fminf(mn, h);
            su += h;
            sq += h * h;
        }
        hmax[nb * 64 + o] = mx;
        hmin[nb * 64 + o] = mn;
    }
    __shared__ float red[4][128];
    red[w][o] = su;
    red[w][64 + o] = sq;
    __syncthreads();
    if (t < 128) {
        float s = red[0][t] + red[1][t] + red[2][t] + red[3][t];
        part[(size_t)(blockIdx.y * 64 + blockIdx.x) * 128 + t] = s;
    }
}

// ---------------------------------------------------------------------------
// K5: reduce 512 block partials -> mean/var -> fused scale/shift.
// ---------------------------------------------------------------------------
__global__ __launch_bounds__(256) void k_stats(const float* __restrict__ part,
                                               const float* __restrict__ gamma,
                                               const float* __restrict__ beta,
                                               float* __restrict__ ab) {
    __shared__ float rs[4][64], rq[4][64];
    const int t = threadIdx.x;
    const int o = t & 63, sl = t >> 6;      // 4 slices of 128 rows
    float s = 0.f, q = 0.f;
    for (int r = sl; r < 512; r += 4) {
        s += part[r * 128 + o];
        q += part[r * 128 + 64 + o];
    }
    rs[sl][o] = s; rq[sl][o] = q;
    __syncthreads();
    if (t < 64) {
        float ss = rs[0][t] + rs[1][t] + rs[2][t] + rs[3][t];
        float qq = rq[0][t] + rq[1][t] + rq[2][t] + rq[3][t];
        const float cnt = (float)BATCH * NPTS * KNN;
        float mean = ss / cnt;
        float var = qq / cnt - mean * mean;
        float rstd = rsqrtf(var + 1e-5f);
        float a = gamma[t] * rstd;
        ab[t] = a;
        ab[64 + t] = beta[t] - mean * a;
    }
}

// ---------------------------------------------------------------------------
// K6: epilogue. Monotone affine+LeakyReLU => max over k is at hmax (scale>=0)
// or hmin (scale<0). LDS transpose for coalesced out[b][o][n] writes.
// ---------------------------------------------------------------------------
__global__ __launch_bounds__(256) void k_out(const float* __restrict__ hmax,
                                             const float* __restrict__ hmin,
                                             const float* __restrict__ ab,
                                             float* __restrict__ out) {
    __shared__ float ts[64][65];
    const int t = threadIdx.x;
    const int b = blockIdx.y;
    const int n0 = blockIdx.x * 64;
#pragma unroll
    for (int i = 0; i < 16; ++i) {
        int flat = t + 256 * i;
        int j = flat >> 6, o = flat & 63;
        size_t nb = ((size_t)b * NPTS + n0 + j) * 64 + o;
        float a = ab[o], sh = ab[64 + o];
        float hval = (a >= 0.f) ? hmax[nb] : hmin[nb];
        float val = a * hval + sh;
        val = (val >= 0.f) ? val : 0.2f * val;
        ts[o][j] = val;
    }
    __syncthreads();
#pragma unroll
    for (int i = 0; i < 16; ++i) {
        int flat = t + 256 * i;
        int o = flat >> 6, j = flat & 63;
        out[((size_t)b * 64 + o) * NPTS + n0 + j] = ts[o][j];
    }
}

// ---------------------------------------------------------------------------
extern "C" void kernel_launch(void* const* d_in, const int* in_sizes, int n_in,
                              void* d_out, int out_size, void* d_ws, size_t ws_size,
                              hipStream_t stream) {
    const float* x     = (const float*)d_in[0];   // (8, 64, 4096)
    const float* W     = (const float*)d_in[1];   // (64, 128)
    const float* gamma = (const float*)d_in[2];   // (64,)
    const float* beta  = (const float*)d_in[3];   // (64,)
    float* out = (float*)d_out;                   // (8, 64, 4096)

    float* ws = (float*)d_ws;
    const size_t BN = (size_t)BATCH * NPTS;       // 32768
    size_t off = 0;
    float* xT   = ws + off; off += BN * 64;
    float* xx   = ws + off; off += BN;
    float* u    = ws + off; off += BN * 64;
    float* v    = ws + off; off += BN * 64;
    float* cval = ws + off; off += BN * NCHUNK * KNN;
    int*   cidx = (int*)(ws + off); off += BN * NCHUNK * KNN;
    int*   idxf = (int*)(ws + off); off += BN * KNN;
    float* hmx  = ws + off; off += BN * 64;
    float* hmn  = ws + off; off += BN * 64;
    float* part = ws + off; off += 512 * 128;
    float* ab   = ws + off; off += 128;
    // total ~16.5M floats (~66 MB), same footprint as the passing round-2 run.

    k_prep  <<<dim3(64, BATCH), 256, 0, stream>>>(x, W, xT, xx, u, v);
    k_knn   <<<dim3(16, NCHUNK, BATCH), 256, 0, stream>>>(xT, xx, cval, cidx);
    k_merge <<<dim3((int)(BN / 256)), 256, 0, stream>>>(cval, cidx, idxf);
    k_gather<<<dim3(64, BATCH), 256, 0, stream>>>(u, v, idxf, hmx, hmn, part);
    k_stats <<<1, 256, 0, stream>>>(part, gamma, beta, ab);
    k_out   <<<dim3(64, BATCH), 256, 0, stream>>>(hmx, hmn, ab, out);
}

// Round 5
// 960.654 us; speedup vs baseline: 1.4306x; 1.2250x over previous
//
#include <hip/hip_runtime.h>
#include <hip/hip_bf16.h>
#include <math.h>

#define NPTS 4096
#define CIN 64
#define COUT 64
#define BATCH 8
#define KNN 20
#define NCHUNK 4
#define CHUNK (NPTS / NCHUNK)
#define TILE 64
#define NTILE (CHUNK / TILE)

// ---------------------------------------------------------------------------
// K0: transpose x -> xT[b][n][c], xx[b][n] = sum_c x^2, and the two small
// GEMMs u[b][n][o] = sum_c (W[o,c]-W[o,64+c])*x[b,c,n],
//       v[b][n][o] = sum_c  W[o,64+c]      *x[b,c,n]
// (h[b,o,n,k] = u[b,n,o] + v[b,idx[b,n,k],o] by linearity of the edge-conv.)
// ---------------------------------------------------------------------------
__global__ __launch_bounds__(256) void k_prep(const float* __restrict__ x,
                                              const float* __restrict__ W,
                                              float* __restrict__ xT,
                                              float* __restrict__ xx,
                                              float* __restrict__ u,
                                              float* __restrict__ v) {
    __shared__ float xs[64][65];   // [c][j], padded: transpose read is conflict-free
    __shared__ float wd[64][64];   // [c][o] = W1 - W2
    __shared__ float wv[64][64];   // [c][o] = W2
    const int t = threadIdx.x;
    const int b = blockIdx.y;
    const int n0 = blockIdx.x * 64;

    const float* xb = x + (size_t)b * CIN * NPTS;
#pragma unroll
    for (int i = 0; i < 16; ++i) {          // load x tile, coalesced per c-row
        int flat = t + 256 * i;             // 4096 elements
        int c = flat >> 6, j = flat & 63;
        xs[c][j] = xb[(size_t)c * NPTS + n0 + j];
    }
#pragma unroll
    for (int i = 0; i < 16; ++i) {          // load/transform W (32 KB, L2-cached)
        int flat = t + 256 * i;
        int o = flat & 63, c = flat >> 6;
        float w1 = W[o * 128 + c];
        float w2 = W[o * 128 + 64 + c];
        wd[c][o] = w1 - w2;
        wv[c][o] = w2;
    }
    __syncthreads();

#pragma unroll
    for (int i = 0; i < 16; ++i) {          // write xT, coalesced over c
        int flat = t + 256 * i;
        int j = flat >> 6, c = flat & 63;
        xT[((size_t)b * NPTS + n0 + j) * 64 + c] = xs[c][j];
    }
    if (t < 64) {                           // xx: sequential over c
        float s = 0.f;
#pragma unroll
        for (int c = 0; c < 64; ++c) { float a = xs[c][t]; s += a * a; }
        xx[b * NPTS + n0 + t] = s;
    }

    // u, v: each thread owns channel o = t&63 for 16 point-columns j = (t>>6)+4i
    const int o = t & 63, jb = t >> 6;
    float au[16], av[16];
#pragma unroll
    for (int i = 0; i < 16; ++i) { au[i] = 0.f; av[i] = 0.f; }
    for (int c = 0; c < 64; ++c) {
        float a = wd[c][o];                 // consecutive o -> conflict-free (2-way, free)
        float p = wv[c][o];
#pragma unroll
        for (int i = 0; i < 16; ++i) {
            float xc = xs[c][jb + 4 * i];   // wave-uniform -> LDS broadcast
            au[i] += a * xc;
            av[i] += p * xc;
        }
    }
#pragma unroll
    for (int i = 0; i < 16; ++i) {
        int j = jb + 4 * i;
        size_t base = ((size_t)b * NPTS + n0 + j) * 64 + o;
        u[base] = au[i];                    // coalesced over o
        v[base] = av[i];
    }
}

// ---------------------------------------------------------------------------
// K1: fused distance + top-20, LDS-staged candidate stream.
// Per block (256 rows x one 1024-candidate chunk): candidates staged in 64-
// cand / 16 KB LDS tiles via reg-staging (issue loads BEFORE compute phase,
// ds_write after barrier -> latency hidden under ~20K-cyc compute). Inner
// loop reads candidates via wave-uniform ds_read_b128 (LDS broadcast, no
// conflict, ~60cyc) instead of per-iteration global loads (R4: 660 cyc/iter
// stall, VALUBusy 45%).
// xxn dropped (constant per row -> rank/tie-invariant for top-k; only idxf is
// consumed downstream). Chain branchless: 20 compares precomputed on old
// vals (shared between adjacent levels), 19x fmed3 + 2 cndmask/level --
// selection semantics identical to the R2/R4-passing chain.
// b = bid&7 = XCD id (hw round-robin): one batch's 1MB xT per 4MB L2 (R4:
// FETCH 66.7->4.2 MB, keep).
// ---------------------------------------------------------------------------
__global__ __launch_bounds__(256, 2) void k_knn(const float* __restrict__ xT,
                                                const float* __restrict__ xx,
                                                float* __restrict__ cval,
                                                int* __restrict__ cidx) {
    __shared__ float cb[TILE * 64];         // 64 cands x 64 ch = 16 KB
    __shared__ float xxs[CHUNK];            // 4 KB
    const int t = threadIdx.x;
    const int bid = blockIdx.x + 16 * (blockIdx.y + NCHUNK * blockIdx.z);
    const int b = bid & 7;                  // XCD id under hw round-robin
    const int slot = bid >> 3;              // 0..63
    const int chunk = slot & (NCHUNK - 1);  // 0..3
    const int rowgrp = slot >> 2;           // 0..15
    const int n = rowgrp * 256 + t;
    const int m0 = chunk * CHUNK;

    const float* xTb = xT + (size_t)b * NPTS * 64;

    // xx chunk -> LDS (published by the tile-0 barrier below)
#pragma unroll
    for (int r = 0; r < 4; ++r)
        xxs[t + 256 * r] = xx[b * NPTS + m0 + t + 256 * r];

    // row -> registers, pinned (R2 lesson: compiler remats global loads)
    float4 row4[16];
    const float4* rp = (const float4*)(xTb + (size_t)n * 64);
#pragma unroll
    for (int q = 0; q < 16; ++q) row4[q] = rp[q];
#pragma unroll
    for (int q = 0; q < 16; ++q) {
        asm volatile("" : "+v"(row4[q].x), "+v"(row4[q].y),
                          "+v"(row4[q].z), "+v"(row4[q].w));
    }

    float vals[KNN];
    int   idxs[KNN];
#pragma unroll
    for (int k = 0; k < KNN; ++k) { vals[k] = -INFINITY; idxs[k] = -1; }

    // stage tile 0 into registers
    const float4* gt0 = (const float4*)(xTb + (size_t)m0 * 64);
    float4 st0 = gt0[t], st1 = gt0[t + 256], st2 = gt0[t + 512], st3 = gt0[t + 768];

    for (int T = 0; T < NTILE; ++T) {
        __syncthreads();                    // all waves done reading cb (tile T-1)
        ((float4*)cb)[t      ] = st0;       // publish tile T
        ((float4*)cb)[t + 256] = st1;
        ((float4*)cb)[t + 512] = st2;
        ((float4*)cb)[t + 768] = st3;
        __syncthreads();
        // issue next tile's loads NOW; they complete during the compute phase
        int Tn = (T + 1 < NTILE) ? T + 1 : T;   // last iter: dummy reload
        const float4* gn = (const float4*)(xTb + (size_t)(m0 + Tn * TILE) * 64);
        st0 = gn[t]; st1 = gn[t + 256]; st2 = gn[t + 512]; st3 = gn[t + 768];

#pragma unroll 2
        for (int mm = 0; mm < TILE; ++mm) {
            const float4* cp = (const float4*)(cb + mm * 64);
            float4 acc = make_float4(0.f, 0.f, 0.f, 0.f);
#pragma unroll
            for (int q = 0; q < 16; ++q) {
                float4 c4 = cp[q];          // uniform addr -> LDS broadcast
                acc.x += row4[q].x * c4.x;
                acc.y += row4[q].y * c4.y;
                acc.z += row4[q].z * c4.z;
                acc.w += row4[q].w * c4.w;
            }
            float inner = (acc.x + acc.y) + (acc.z + acc.w);
            float d = 2.f * inner - xxs[T * TILE + mm];
            const int midx = m0 + T * TILE + mm;
            bool c[KNN];
#pragma unroll
            for (int k = 0; k < KNN; ++k) c[k] = (vals[k] >= d);  // old vals
#pragma unroll
            for (int j = KNN - 1; j >= 1; --j) {
                vals[j] = __builtin_amdgcn_fmed3f(d, vals[j - 1], vals[j]);
                idxs[j] = c[j] ? idxs[j] : (c[j - 1] ? midx : idxs[j - 1]);
            }
            vals[0] = fmaxf(vals[0], d);
            idxs[0] = c[0] ? idxs[0] : midx;
        }
    }

    size_t rbase = ((size_t)(b * NPTS + n) * NCHUNK + chunk) * KNN;
#pragma unroll
    for (int k = 0; k < KNN; ++k) { cval[rbase + k] = vals[k]; cidx[rbase + k] = idxs[k]; }
}

// ---------------------------------------------------------------------------
// K2: K-way merge of the per-chunk sorted top-20 lists. All array indexing is
// compile-time (p[c], c unrolled) -> registers, no scratch. Strict '>' keeps
// the lowest chunk on ties (chunks cover ascending m) = lowest-index-first.
// ---------------------------------------------------------------------------
__global__ __launch_bounds__(256) void k_merge(const float* __restrict__ cval,
                                               const int* __restrict__ cidx,
                                               int* __restrict__ idxf) {
    const int r = blockIdx.x * 256 + threadIdx.x;   // 0..B*N-1
    const float* v0 = cval + (size_t)r * (NCHUNK * KNN);
    const int*   i0 = cidx + (size_t)r * (NCHUNK * KNN);
    int p[NCHUNK];
#pragma unroll
    for (int c = 0; c < NCHUNK; ++c) p[c] = 0;
    int* op = idxf + (size_t)r * KNN;
    for (int k = 0; k < KNN; ++k) {
        float best = -INFINITY; int besti = 0, bc = 0;
#pragma unroll
        for (int c = 0; c < NCHUNK; ++c) {
            float hv = v0[c * KNN + p[c]];          // L1-cached re-reads
            int   hi = i0[c * KNN + p[c]];
            bool g = hv > best;
            best = g ? hv : best;
            besti = g ? hi : besti;
            bc = g ? c : bc;
        }
        op[k] = besti;
#pragma unroll
        for (int c = 0; c < NCHUNK; ++c) p[c] += (bc == c);
    }
}

// ---------------------------------------------------------------------------
// K4: single gather pass: h = u[n][o] + v[m][o]; accumulate sum/sumsq per
// channel (block partials, no atomics -> deterministic) and per-(n,o) max/min.
// Wave = 64 lanes = 64 channels; v rows are 256 B coalesced L2-resident reads.
// ---------------------------------------------------------------------------
__global__ __launch_bounds__(256) void k_gather(const float* __restrict__ u,
                                                const float* __restrict__ v,
                                                const int* __restrict__ idxf,
                                                float* __restrict__ hmax,
                                                float* __restrict__ hmin,
                                                float* __restrict__ part) {
    const int t = threadIdx.x;
    const int o = t & 63, w = t >> 6;
    const int b = blockIdx.y;
    const int n0 = blockIdx.x * 64;
    const float* vb = v + (size_t)b * NPTS * 64;
    float su = 0.f, sq = 0.f;
    for (int r = 0; r < 16; ++r) {
        int n = n0 + w + 4 * r;
        size_t nb = (size_t)b * NPTS + n;
        float hu = u[nb * 64 + o];
        const int* ip = idxf + nb * KNN;    // wave-uniform reads
        float mx = -INFINITY, mn = INFINITY;
#pragma unroll 4
        for (int k = 0; k < KNN; ++k) {
            int m = ip[k];
            float h = hu + vb[(size_t)m * 64 + o];
            mx = fmaxf(mx, h);
            mn = fminf(mn, h);
            su += h;
            sq += h * h;
        }
        hmax[nb * 64 + o] = mx;
        hmin[nb * 64 + o] = mn;
    }
    __shared__ float red[4][128];
    red[w][o] = su;
    red[w][64 + o] = sq;
    __syncthreads();
    if (t < 128) {
        float s = red[0][t] + red[1][t] + red[2][t] + red[3][t];
        part[(size_t)(blockIdx.y * 64 + blockIdx.x) * 128 + t] = s;
    }
}

// ---------------------------------------------------------------------------
// K5: reduce 512 block partials -> mean/var -> fused scale/shift.
// ---------------------------------------------------------------------------
__global__ __launch_bounds__(256) void k_stats(const float* __restrict__ part,
                                               const float* __restrict__ gamma,
                                               const float* __restrict__ beta,
                                               float* __restrict__ ab) {
    __shared__ float rs[4][64], rq[4][64];
    const int t = threadIdx.x;
    const int o = t & 63, sl = t >> 6;      // 4 slices of 128 rows
    float s = 0.f, q = 0.f;
    for (int r = sl; r < 512; r += 4) {
        s += part[r * 128 + o];
        q += part[r * 128 + 64 + o];
    }
    rs[sl][o] = s; rq[sl][o] = q;
    __syncthreads();
    if (t < 64) {
        float ss = rs[0][t] + rs[1][t] + rs[2][t] + rs[3][t];
        float qq = rq[0][t] + rq[1][t] + rq[2][t] + rq[3][t];
        const float cnt = (float)BATCH * NPTS * KNN;
        float mean = ss / cnt;
        float var = qq / cnt - mean * mean;
        float rstd = rsqrtf(var + 1e-5f);
        float a = gamma[t] * rstd;
        ab[t] = a;
        ab[64 + t] = beta[t] - mean * a;
    }
}

// ---------------------------------------------------------------------------
// K6: epilogue. Monotone affine+LeakyReLU => max over k is at hmax (scale>=0)
// or hmin (scale<0). LDS transpose for coalesced out[b][o][n] writes.
// ---------------------------------------------------------------------------
__global__ __launch_bounds__(256) void k_out(const float* __restrict__ hmax,
                                             const float* __restrict__ hmin,
                                             const float* __restrict__ ab,
                                             float* __restrict__ out) {
    __shared__ float ts[64][65];
    const int t = threadIdx.x;
    const int b = blockIdx.y;
    const int n0 = blockIdx.x * 64;
#pragma unroll
    for (int i = 0; i < 16; ++i) {
        int flat = t + 256 * i;
        int j = flat >> 6, o = flat & 63;
        size_t nb = ((size_t)b * NPTS + n0 + j) * 64 + o;
        float a = ab[o], sh = ab[64 + o];
        float hval = (a >= 0.f) ? hmax[nb] : hmin[nb];
        float val = a * hval + sh;
        val = (val >= 0.f) ? val : 0.2f * val;
        ts[o][j] = val;
    }
    __syncthreads();
#pragma unroll
    for (int i = 0; i < 16; ++i) {
        int flat = t + 256 * i;
        int o = flat >> 6, j = flat & 63;
        out[((size_t)b * 64 + o) * NPTS + n0 + j] = ts[o][j];
    }
}

// ---------------------------------------------------------------------------
extern "C" void kernel_launch(void* const* d_in, const int* in_sizes, int n_in,
                              void* d_out, int out_size, void* d_ws, size_t ws_size,
                              hipStream_t stream) {
    const float* x     = (const float*)d_in[0];   // (8, 64, 4096)
    const float* W     = (const float*)d_in[1];   // (64, 128)
    const float* gamma = (const float*)d_in[2];   // (64,)
    const float* beta  = (const float*)d_in[3];   // (64,)
    float* out = (float*)d_out;                   // (8, 64, 4096)

    float* ws = (float*)d_ws;
    const size_t BN = (size_t)BATCH * NPTS;       // 32768
    size_t off = 0;
    float* xT   = ws + off; off += BN * 64;
    float* xx   = ws + off; off += BN;
    float* u    = ws + off; off += BN * 64;
    float* v    = ws + off; off += BN * 64;
    float* cval = ws + off; off += BN * NCHUNK * KNN;
    int*   cidx = (int*)(ws + off); off += BN * NCHUNK * KNN;
    int*   idxf = (int*)(ws + off); off += BN * KNN;
    float* hmx  = ws + off; off += BN * 64;
    float* hmn  = ws + off; off += BN * 64;
    float* part = ws + off; off += 512 * 128;
    float* ab   = ws + off; off += 128;
    // total ~16.5M floats (~66 MB), all buffers fully written before read.

    k_prep  <<<dim3(64, BATCH), 256, 0, stream>>>(x, W, xT, xx, u, v);
    k_knn   <<<dim3(16, NCHUNK, BATCH), 256, 0, stream>>>(xT, xx, cval, cidx);
    k_merge <<<dim3((int)(BN / 256)), 256, 0, stream>>>(cval, cidx, idxf);
    k_gather<<<dim3(64, BATCH), 256, 0, stream>>>(u, v, idxf, hmx, hmn, part);
    k_stats <<<1, 256, 0, stream>>>(part, gamma, beta, ab);
    k_out   <<<dim3(64, BATCH), 256, 0, stream>>>(hmx, hmn, ab, out);
}